// Round 1
// baseline (37.511 us; speedup 1.0000x reference)
//
#include <hip/hip_runtime.h>

// Problem dims (fixed by the reference file)
#define NT      2097152     // NUM_LAYERS * BATCH * SEQ
#define NE      8           // experts
#define MASKN   65536       // BATCH * SEQ (power of two)
#define NBLK    1024
#define NTHR    256
#define NACC    18          // [ent_sum, mask_sum, r_acc[8], p_acc[8]]

#define TOP_P_F       0.8f
#define ENT_THR_F     0.5f

__global__ __launch_bounds__(NTHR) void dynmole_main(
    const float* __restrict__ logits, const int* __restrict__ amask,
    float* __restrict__ acc)
{
    int tid = blockIdx.x * NTHR + threadIdx.x;
    const int stride = NBLK * NTHR;

    float ent_acc = 0.f, m_acc = 0.f;
    float r_acc[NE], p_acc[NE];
#pragma unroll
    for (int e = 0; e < NE; ++e) { r_acc[e] = 0.f; p_acc[e] = 0.f; }

    for (int t = tid; t < NT; t += stride) {
        const float4* g4 = reinterpret_cast<const float4*>(logits + (size_t)t * NE);
        float4 lo = g4[0];
        float4 hi = g4[1];
        float p[NE] = {lo.x, lo.y, lo.z, lo.w, hi.x, hi.y, hi.z, hi.w};

        // softmax (max-subtracted, fast exp)
        float mx = fmaxf(fmaxf(fmaxf(p[0], p[1]), fmaxf(p[2], p[3])),
                         fmaxf(fmaxf(p[4], p[5]), fmaxf(p[6], p[7])));
        float s = 0.f;
#pragma unroll
        for (int i = 0; i < NE; ++i) { p[i] = __expf(p[i] - mx); s += p[i]; }
        float inv = __builtin_amdgcn_rcpf(s);
        float sq = 0.f;
#pragma unroll
        for (int i = 0; i < NE; ++i) { p[i] *= inv; sq = fmaf(p[i], p[i], sq); }

        // Tsallis entropy, q=2:  ent = (1 - sum p^2) / (q-1) = 1 - sum p^2
        float ent = 1.f - sq;
        ent_acc += ent;

        float fm = (float)amask[t & (MASKN - 1)];
        m_acc += fm;

        bool high = ent > ENT_THR_F;

        // top-p / keep-top-k mask without sorting:
        // rank(e) = #{f : p_f > p_e  or (p_f == p_e and f < e)}   (stable desc sort)
        // cum(e)  = inclusive cumsum in sorted order
        //         = p_e + sum over "preceding" f of p_f
        // mask(e) = rank < 2  ||  cum <= TOP_P   (|| high-entropy override)
#pragma unroll
        for (int e = 0; e < NE; ++e) {
            int   rank = 0;
            float cum  = p[e];
#pragma unroll
            for (int f = 0; f < NE; ++f) {
                if (f == e) continue;
                bool sel = (f < e) ? (p[f] >= p[e]) : (p[f] > p[e]);
                rank += sel ? 1 : 0;
                cum  += sel ? p[f] : 0.f;
            }
            float mk = (high || (rank < 2) || (cum <= TOP_P_F)) ? 1.f : 0.f;
            r_acc[e] = fmaf(p[e] * mk, fm, r_acc[e]);
            p_acc[e] = fmaf(p[e],      fm, p_acc[e]);
        }
    }

    // ---- block reduction ----
    float v[NACC];
    v[0] = ent_acc; v[1] = m_acc;
#pragma unroll
    for (int e = 0; e < NE; ++e) { v[2 + e] = r_acc[e]; v[10 + e] = p_acc[e]; }

#pragma unroll
    for (int off = 32; off >= 1; off >>= 1) {
#pragma unroll
        for (int c = 0; c < NACC; ++c)
            v[c] += __shfl_down(v[c], off, 64);
    }

    __shared__ float lds[NTHR / 64][NACC];
    int lane = threadIdx.x & 63;
    int wv   = threadIdx.x >> 6;
    if (lane == 0) {
#pragma unroll
        for (int c = 0; c < NACC; ++c) lds[wv][c] = v[c];
    }
    __syncthreads();
    if (threadIdx.x < NACC) {
        float sum = 0.f;
#pragma unroll
        for (int w = 0; w < NTHR / 64; ++w) sum += lds[w][threadIdx.x];
        atomicAdd(&acc[threadIdx.x], sum);
    }
}

__global__ void dynmole_final(const float* __restrict__ acc, float* __restrict__ out)
{
    float ent_mean = acc[0] / (float)NT;
    float denom = acc[1] + 1e-8f;
    float inv_d = 1.0f / denom;
    float lb = 0.f;
#pragma unroll
    for (int e = 0; e < NE; ++e)
        lb += (acc[2 + e] * inv_d) * (acc[10 + e] * inv_d);
    lb *= (float)NE;
    out[0] = 0.01f * ent_mean + 0.001f * lb;
}

extern "C" void kernel_launch(void* const* d_in, const int* in_sizes, int n_in,
                              void* d_out, int out_size, void* d_ws, size_t ws_size,
                              hipStream_t stream) {
    const float* logits = (const float*)d_in[0];
    const int*   amask  = (const int*)d_in[1];
    float*       out    = (float*)d_out;
    float*       acc    = (float*)d_ws;

    hipMemsetAsync(acc, 0, NACC * sizeof(float), stream);
    dynmole_main<<<NBLK, NTHR, 0, stream>>>(logits, amask, acc);
    dynmole_final<<<1, 1, 0, stream>>>(acc, out);
}

// Round 2
// 31.046 us; speedup vs baseline: 1.2082x; 1.2082x over previous
//
#include <hip/hip_runtime.h>

// Problem dims (fixed by the reference file)
#define NT      2097152     // NUM_LAYERS * BATCH * SEQ
#define NE      8           // experts
#define MASKN   65536       // BATCH * SEQ (power of two)
#define NBLK    2048
#define NTHR    256
#define TPT     (NT / (NBLK * NTHR))   // 4 tokens per thread
#define NACC    18          // [ent_sum, mask_sum, r_acc[8], p_acc[8]]

#define TOP_P_F       0.8f
#define ENT_THR_F     0.5f

__global__ __launch_bounds__(NTHR) void dynmole_main(
    const float* __restrict__ logits, const int* __restrict__ amask,
    float* __restrict__ part)
{
    int tid = blockIdx.x * NTHR + threadIdx.x;
    const int stride = NBLK * NTHR;

    float ent_acc = 0.f, m_acc = 0.f;
    float r_acc[NE], p_acc[NE];
#pragma unroll
    for (int e = 0; e < NE; ++e) { r_acc[e] = 0.f; p_acc[e] = 0.f; }

#pragma unroll
    for (int k = 0; k < TPT; ++k) {
        int t = tid + k * stride;
        const float4* g4 = reinterpret_cast<const float4*>(logits + (size_t)t * NE);
        float4 lo = g4[0];
        float4 hi = g4[1];
        float p[NE] = {lo.x, lo.y, lo.z, lo.w, hi.x, hi.y, hi.z, hi.w};

        // softmax (max-subtracted, fast exp)
        float mx = fmaxf(fmaxf(fmaxf(p[0], p[1]), fmaxf(p[2], p[3])),
                         fmaxf(fmaxf(p[4], p[5]), fmaxf(p[6], p[7])));
        float s = 0.f;
#pragma unroll
        for (int i = 0; i < NE; ++i) { p[i] = __expf(p[i] - mx); s += p[i]; }
        float inv = __builtin_amdgcn_rcpf(s);
        float sq = 0.f;
#pragma unroll
        for (int i = 0; i < NE; ++i) { p[i] *= inv; sq = fmaf(p[i], p[i], sq); }

        // Tsallis entropy, q=2:  ent = 1 - sum p^2
        float ent = 1.f - sq;
        ent_acc += ent;

        float fm = (float)amask[t & (MASKN - 1)];
        m_acc += fm;

        // ---- top-p / keep-top-k via Batcher odd-even sorting network ----
        // kept set is a prefix of the descending sort; threshold = last kept value
        float sp[NE] = {p[0], p[1], p[2], p[3], p[4], p[5], p[6], p[7]};
#define CE(i, j) do { float _a = sp[i], _b = sp[j]; sp[i] = fmaxf(_a, _b); sp[j] = fminf(_a, _b); } while (0)
        CE(0,1); CE(2,3); CE(4,5); CE(6,7);
        CE(0,2); CE(1,3); CE(4,6); CE(5,7);
        CE(1,2); CE(5,6);
        CE(0,4); CE(1,5); CE(2,6); CE(3,7);
        CE(2,4); CE(3,5);
        CE(1,2); CE(3,4); CE(5,6);
#undef CE
        // inclusive cumsum in sorted order; keep i if i<2 or cum_i <= TOP_P
        float run = sp[0] + sp[1];
        float thr = sp[1];
        run += sp[2]; thr = (run <= TOP_P_F) ? sp[2] : thr;
        run += sp[3]; thr = (run <= TOP_P_F) ? sp[3] : thr;
        run += sp[4]; thr = (run <= TOP_P_F) ? sp[4] : thr;
        run += sp[5]; thr = (run <= TOP_P_F) ? sp[5] : thr;
        run += sp[6]; thr = (run <= TOP_P_F) ? sp[6] : thr;
        run += sp[7]; thr = (run <= TOP_P_F) ? sp[7] : thr;
        // high-entropy override: keep everything
        thr = (ent > ENT_THR_F) ? -1.f : thr;

#pragma unroll
        for (int e = 0; e < NE; ++e) {
            float pf = p[e] * fm;
            p_acc[e] += pf;
            r_acc[e] += (p[e] >= thr) ? pf : 0.f;
        }
    }

    // ---- block reduction ----
    float v[NACC];
    v[0] = ent_acc; v[1] = m_acc;
#pragma unroll
    for (int e = 0; e < NE; ++e) { v[2 + e] = r_acc[e]; v[10 + e] = p_acc[e]; }

#pragma unroll
    for (int off = 32; off >= 1; off >>= 1) {
#pragma unroll
        for (int c = 0; c < NACC; ++c)
            v[c] += __shfl_down(v[c], off, 64);
    }

    __shared__ float lds[NTHR / 64][NACC];
    int lane = threadIdx.x & 63;
    int wv   = threadIdx.x >> 6;
    if (lane == 0) {
#pragma unroll
        for (int c = 0; c < NACC; ++c) lds[wv][c] = v[c];
    }
    __syncthreads();
    if (threadIdx.x < NACC) {
        float sum = 0.f;
#pragma unroll
        for (int w = 0; w < NTHR / 64; ++w) sum += lds[w][threadIdx.x];
        part[threadIdx.x * NBLK + blockIdx.x] = sum;   // transposed: coalesced final reads
    }
}

__global__ __launch_bounds__(1024) void dynmole_final(
    const float* __restrict__ part, float* __restrict__ out)
{
    int tid  = threadIdx.x;
    int lane = tid & 63;
    int wv   = tid >> 6;

    float v[NACC];
#pragma unroll
    for (int c = 0; c < NACC; ++c)
        v[c] = part[c * NBLK + tid] + part[c * NBLK + tid + 1024];

#pragma unroll
    for (int off = 32; off >= 1; off >>= 1) {
#pragma unroll
        for (int c = 0; c < NACC; ++c)
            v[c] += __shfl_down(v[c], off, 64);
    }

    __shared__ float lds[16][NACC];
    if (lane == 0) {
#pragma unroll
        for (int c = 0; c < NACC; ++c) lds[wv][c] = v[c];
    }
    __syncthreads();

    if (tid == 0) {
        float acc[NACC];
#pragma unroll
        for (int c = 0; c < NACC; ++c) {
            float s = 0.f;
            for (int w = 0; w < 16; ++w) s += lds[w][c];
            acc[c] = s;
        }
        float ent_mean = acc[0] / (float)NT;
        float denom = acc[1] + 1e-8f;
        float inv_d = 1.0f / denom;
        float lb = 0.f;
#pragma unroll
        for (int e = 0; e < NE; ++e)
            lb += (acc[2 + e] * inv_d) * (acc[10 + e] * inv_d);
        lb *= (float)NE;
        out[0] = 0.01f * ent_mean + 0.001f * lb;
    }
}

extern "C" void kernel_launch(void* const* d_in, const int* in_sizes, int n_in,
                              void* d_out, int out_size, void* d_ws, size_t ws_size,
                              hipStream_t stream) {
    const float* logits = (const float*)d_in[0];
    const int*   amask  = (const int*)d_in[1];
    float*       out    = (float*)d_out;
    float*       part   = (float*)d_ws;

    dynmole_main<<<NBLK, NTHR, 0, stream>>>(logits, amask, part);
    dynmole_final<<<1, 1024, 0, stream>>>(part, out);
}